// Round 6
// baseline (810.038 us; speedup 1.0000x reference)
//
#include <hip/hip_runtime.h>
#include <hip/hip_bf16.h>

// ---------------- constants ----------------
#define NUM_USERS 50000
#define NUM_ITEMS 20000
#define NUM_NODES (NUM_USERS + NUM_ITEMS)
#define FEAT_DIM 768
#define HID 128
#define H1DIM 512
#define LN_EPS 1e-5f
#define ALPHA 0.25f
#define NBKT 137  // ceil(70000/512) coarse buckets

typedef __attribute__((ext_vector_type(8))) short short8;
typedef __attribute__((ext_vector_type(4))) float floatx4;

// bf16 round-to-nearest-even
static __device__ inline unsigned short f2bf(float f) {
  unsigned int u = __float_as_uint(f);
  u += 0x7fffu + ((u >> 16) & 1u);
  return (unsigned short)(u >> 16);
}
static __device__ inline float bflo(unsigned int u) {
  return __uint_as_float(u << 16);
}
static __device__ inline float bfhi(unsigned int u) {
  return __uint_as_float(u & 0xffff0000u);
}

// -------- cast fp32 -> bf16, 8 elements/thread, exact grid -------------------
__global__ __launch_bounds__(256) void cast_bf16(
    const float* __restrict__ in, unsigned short* __restrict__ out) {
  size_t i = (size_t)blockIdx.x * 256 + threadIdx.x;
  float4 u = ((const float4*)in)[i * 2];
  float4 v = ((const float4*)in)[i * 2 + 1];
  union { unsigned short s[8]; uint4 q; } p;
  p.s[0] = f2bf(u.x); p.s[1] = f2bf(u.y); p.s[2] = f2bf(u.z); p.s[3] = f2bf(u.w);
  p.s[4] = f2bf(v.x); p.s[5] = f2bf(v.y); p.s[6] = f2bf(v.z); p.s[7] = f2bf(v.w);
  ((uint4*)out)[i] = p.q;
}

// -------- transpose+cast: W[K x N] fp32 -> Wt[N x K] bf16 --------------------
__global__ __launch_bounds__(256) void transpose_cast(
    const float* __restrict__ W, unsigned short* __restrict__ Wt,
    int K, int N) {
  __shared__ float tile[32][33];
  int tx = threadIdx.x, ty = threadIdx.y;
  int bx = blockIdx.x, by = blockIdx.y;
#pragma unroll
  for (int kk = 0; kk < 4; kk++)
    tile[ty + kk * 8][tx] = W[(size_t)(by * 32 + ty + kk * 8) * N + bx * 32 + tx];
  __syncthreads();
#pragma unroll
  for (int kk = 0; kk < 4; kk++)
    Wt[(size_t)(bx * 32 + ty + kk * 8) * K + by * 32 + tx] =
        f2bf(tile[tx][ty + kk * 8]);
}

// -------- bf16 MFMA GEMM: C(MxN) fp32 = A(MxK) . Bt(NxK)^T + bias ------------
__global__ __launch_bounds__(256) void gemm_mfma_bias(
    const unsigned short* __restrict__ A, const unsigned short* __restrict__ Bt,
    const float* __restrict__ bias, float* __restrict__ C,
    int M, int N, int K) {
  __shared__ __align__(16) unsigned short As[128 * 32];
  __shared__ __align__(16) unsigned short Bs[128 * 32];
  const int tid = threadIdx.x;
  const int wave = tid >> 6, lane = tid & 63;
  const int quad = lane >> 4, l16 = lane & 15;
  const int wm = wave >> 1, wn = wave & 1;
  const int bm = blockIdx.y * 128, bn = blockIdx.x * 128;

  floatx4 acc[4][4];
#pragma unroll
  for (int i = 0; i < 4; i++)
#pragma unroll
    for (int j = 0; j < 4; j++) acc[i][j] = (floatx4){0.f, 0.f, 0.f, 0.f};

  const int srow = lane >> 2;
  const int scol = (lane & 3) * 8;

  for (int k0 = 0; k0 < K; k0 += 32) {
#pragma unroll
    for (int i = 0; i < 2; i++) {
      int c = wave * 2 + i;
      int arow = bm + c * 16 + srow;
      if (arow >= M) arow = M - 1;
      const unsigned short* ga = A + (size_t)arow * K + k0 + scol;
      __builtin_amdgcn_global_load_lds(
          (const __attribute__((address_space(1))) unsigned int*)(uintptr_t)ga,
          (__attribute__((address_space(3))) unsigned int*)(uintptr_t)(As + c * 512),
          16, 0, 0);
      int brow = bn + c * 16 + srow;
      const unsigned short* gb = Bt + (size_t)brow * K + k0 + scol;
      __builtin_amdgcn_global_load_lds(
          (const __attribute__((address_space(1))) unsigned int*)(uintptr_t)gb,
          (__attribute__((address_space(3))) unsigned int*)(uintptr_t)(Bs + c * 512),
          16, 0, 0);
    }
    __syncthreads();

    short8 af[4], bf[4];
#pragma unroll
    for (int i = 0; i < 4; i++) {
      af[i] = *(const short8*)&As[(wm * 64 + i * 16 + l16) * 32 + quad * 8];
      bf[i] = *(const short8*)&Bs[(wn * 64 + i * 16 + l16) * 32 + quad * 8];
    }
#pragma unroll
    for (int i = 0; i < 4; i++)
#pragma unroll
      for (int j = 0; j < 4; j++)
        acc[i][j] = __builtin_amdgcn_mfma_f32_16x16x32_bf16(af[i], bf[j],
                                                            acc[i][j], 0, 0, 0);
    __syncthreads();
  }

#pragma unroll
  for (int i = 0; i < 4; i++) {
    int row0 = bm + wm * 64 + i * 16 + quad * 4;
#pragma unroll
    for (int j = 0; j < 4; j++) {
      int col = bn + wn * 64 + j * 16 + l16;
      float bv = bias[col];
#pragma unroll
      for (int r = 0; r < 4; r++) {
        int row = row0 + r;
        if (row < M) C[(size_t)row * N + col] = acc[i][j][r] + bv;
      }
    }
  }
}

// ---- LayerNorm+ReLU width 512, fp32 in -> bf16 out --------------------------
__global__ __launch_bounds__(256) void ln_relu_w512_bf16(
    const float* __restrict__ X, const float* __restrict__ g,
    const float* __restrict__ be, unsigned short* __restrict__ O) {
  int row = blockIdx.x, t = threadIdx.x;
  const float* x = X + (size_t)row * H1DIM;
  float v0 = x[t], v1 = x[t + 256];
  float s = v0 + v1, q = v0 * v0 + v1 * v1;
#pragma unroll
  for (int off = 32; off > 0; off >>= 1) {
    s += __shfl_down(s, off);
    q += __shfl_down(q, off);
  }
  __shared__ float ss[4], qq[4];
  int lane = t & 63, wid = t >> 6;
  if (lane == 0) { ss[wid] = s; qq[wid] = q; }
  __syncthreads();
  float S = ss[0] + ss[1] + ss[2] + ss[3];
  float Q = qq[0] + qq[1] + qq[2] + qq[3];
  float mu = S * (1.f / 512.f);
  float var = Q * (1.f / 512.f) - mu * mu;
  float rs = rsqrtf(var + LN_EPS);
  float y0 = (v0 - mu) * rs * g[t] + be[t];
  float y1 = (v1 - mu) * rs * g[t + 256] + be[t + 256];
  unsigned short* o = O + (size_t)row * H1DIM;
  o[t] = f2bf(fmaxf(y0, 0.f));
  o[t + 256] = f2bf(fmaxf(y1, 0.f));
}

// ---------------- LayerNorm+ReLU, width 128, one wave per row ----------------
__global__ __launch_bounds__(256) void ln_relu_w128(
    float* __restrict__ X, const float* __restrict__ g,
    const float* __restrict__ be, int rows) {
  int gwid = (blockIdx.x * blockDim.x + threadIdx.x) >> 6;
  if (gwid >= rows) return;
  int lane = threadIdx.x & 63;
  float* x = X + (size_t)gwid * HID;
  float v0 = x[lane], v1 = x[lane + 64];
  float s = v0 + v1, q = v0 * v0 + v1 * v1;
#pragma unroll
  for (int off = 32; off > 0; off >>= 1) {
    s += __shfl_down(s, off);
    q += __shfl_down(q, off);
  }
  s = __shfl(s, 0);
  q = __shfl(q, 0);
  float mu = s * (1.f / 128.f);
  float var = q * (1.f / 128.f) - mu * mu;
  float rs = rsqrtf(var + LN_EPS);
  float y0 = (v0 - mu) * rs * g[lane] + be[lane];
  float y1 = (v1 - mu) * rs * g[lane + 64] + be[lane + 64];
  x[lane] = fmaxf(y0, 0.f);
  x[lane + 64] = fmaxf(y1, 0.f);
}

// ---- GEMM3 (128x128) + L2-normalize, 4 rows/block ---------------------------
__global__ __launch_bounds__(128) void gemm3_norm4(
    const float* __restrict__ H, const float* __restrict__ W3,
    const float* __restrict__ b3, float* __restrict__ meta) {
  int r0 = blockIdx.x * 4, t = threadIdx.x;
  __shared__ float hrow[4][HID];
#pragma unroll
  for (int r = 0; r < 4; r++) hrow[r][t] = H[(size_t)(r0 + r) * HID + t];
  __syncthreads();
  float s0 = 0.f, s1 = 0.f, s2 = 0.f, s3 = 0.f;
#pragma unroll 4
  for (int k = 0; k < HID; k++) {
    float w = W3[k * HID + t];
    s0 = fmaf(hrow[0][k], w, s0);
    s1 = fmaf(hrow[1][k], w, s1);
    s2 = fmaf(hrow[2][k], w, s2);
    s3 = fmaf(hrow[3][k], w, s3);
  }
  float b = b3[t];
  s0 += b; s1 += b; s2 += b; s3 += b;
  float q0 = s0 * s0, q1 = s1 * s1, q2 = s2 * s2, q3 = s3 * s3;
#pragma unroll
  for (int off = 32; off > 0; off >>= 1) {
    q0 += __shfl_down(q0, off);
    q1 += __shfl_down(q1, off);
    q2 += __shfl_down(q2, off);
    q3 += __shfl_down(q3, off);
  }
  __shared__ float qs[4][2];
  if ((t & 63) == 0) {
    int w = t >> 6;
    qs[0][w] = q0; qs[1][w] = q1; qs[2][w] = q2; qs[3][w] = q3;
  }
  __syncthreads();
  float n0 = fmaxf(sqrtf(qs[0][0] + qs[0][1]), 1e-12f);
  float n1 = fmaxf(sqrtf(qs[1][0] + qs[1][1]), 1e-12f);
  float n2 = fmaxf(sqrtf(qs[2][0] + qs[2][1]), 1e-12f);
  float n3 = fmaxf(sqrtf(qs[3][0] + qs[3][1]), 1e-12f);
  meta[(size_t)(r0 + 0) * HID + t] = s0 / n0;
  meta[(size_t)(r0 + 1) * HID + t] = s1 / n1;
  meta[(size_t)(r0 + 2) * HID + t] = s2 / n2;
  meta[(size_t)(r0 + 3) * HID + t] = s3 / n3;
}

// --------- build e0: out = alpha*e0 (fp32), x0 chunk-major bf16 --------------
// x0_cm[chunk][node][16 feats] as 8 uints per (chunk,node). Thread = one uint.
__global__ __launch_bounds__(256) void build_e0_cm(
    const float* __restrict__ emb, const float* __restrict__ meta,
    const float* __restrict__ mw_p, unsigned int* __restrict__ x0c,
    float* __restrict__ out) {
  size_t i = (size_t)blockIdx.x * 256 + threadIdx.x;  // 70000*64 uints, exact
  int node = (int)(i >> 6);
  int u6 = (int)(i & 63);
  int chunk = u6 >> 3, fl = u6 & 7;
  int f0 = chunk * 16 + fl * 2;
  float2 e = *(const float2*)&emb[(size_t)node * HID + f0];
  if (node >= NUM_USERS) {
    float2 m = *(const float2*)&meta[(size_t)(node - NUM_USERS) * HID + f0];
    float w = mw_p[0];
    e.x += w * m.x;
    e.y += w * m.y;
  }
  *(float2*)&out[(size_t)node * HID + f0] = make_float2(ALPHA * e.x, ALPHA * e.y);
  unsigned pk = (unsigned)f2bf(e.x) | ((unsigned)f2bf(e.y) << 16);
  x0c[((size_t)chunk * NUM_NODES + node) * 8 + fl] = pk;
}

// ======== atomic-free CSR build: two-level bucket sort =======================
__global__ __launch_bounds__(256) void p1_hist(const int* __restrict__ dst,
                                               int* __restrict__ ghist,
                                               int E, int NBL) {
  __shared__ int h[NBKT];
  int t = threadIdx.x;
  if (t < NBKT) h[t] = 0;
  __syncthreads();
  int base = blockIdx.x * 8192;
  for (int i = t; i < 8192; i += 256) {
    int e = base + i;
    if (e < E) atomicAdd(&h[dst[e] >> 9], 1);
  }
  __syncthreads();
  if (t < NBKT) ghist[t * NBL + blockIdx.x] = h[t];
}

__global__ __launch_bounds__(256) void scan_a(const int* __restrict__ in,
                                              int* __restrict__ outp,
                                              int* __restrict__ bsum, int n) {
  int i = blockIdx.x * 256 + threadIdx.x;
  int v = (i < n) ? in[i] : 0;
  int lane = threadIdx.x & 63, wid = threadIdx.x >> 6;
  int s = v;
#pragma unroll
  for (int off = 1; off < 64; off <<= 1) {
    int u = __shfl_up(s, off);
    if (lane >= off) s += u;
  }
  __shared__ int wsum[4];
  if (lane == 63) wsum[wid] = s;
  __syncthreads();
  int add = 0;
  for (int w = 0; w < wid; w++) add += wsum[w];
  int incl = s + add;
  if (i < n) outp[i] = incl - v;
  if (threadIdx.x == 255) bsum[blockIdx.x] = incl;
}

__global__ __launch_bounds__(512) void scan_b(int* __restrict__ bsum, int nb) {
  int t = threadIdx.x;
  int v = (t < nb) ? bsum[t] : 0;
  int lane = t & 63, wid = t >> 6;
  int s = v;
#pragma unroll
  for (int off = 1; off < 64; off <<= 1) {
    int u = __shfl_up(s, off);
    if (lane >= off) s += u;
  }
  __shared__ int ws[8];
  if (lane == 63) ws[wid] = s;
  __syncthreads();
  int add = 0;
  for (int w = 0; w < wid; w++) add += ws[w];
  if (t < nb) bsum[t] = s + add - v;
}

__global__ __launch_bounds__(256) void scan_c(int* __restrict__ outp,
                                              const int* __restrict__ bsum,
                                              int n) {
  int i = blockIdx.x * 256 + threadIdx.x;
  if (i < n) outp[i] += bsum[blockIdx.x];
}

__global__ __launch_bounds__(256) void p1_scatter(
    const int* __restrict__ src, const int* __restrict__ dst,
    const int* __restrict__ gscan, unsigned long long* __restrict__ pairs,
    int E, int NBL) {
  __shared__ int cur[NBKT];
  int t = threadIdx.x;
  if (t < NBKT) cur[t] = gscan[t * NBL + blockIdx.x];
  __syncthreads();
  int base = blockIdx.x * 8192;
  for (int i = t; i < 8192; i += 256) {
    int e = base + i;
    if (e < E) {
      int d = dst[e];
      int pos = atomicAdd(&cur[d >> 9], 1);
      pairs[pos] = ((unsigned long long)(unsigned)d << 32) | (unsigned)src[e];
    }
  }
}

__global__ __launch_bounds__(512) void p2_build(
    const unsigned long long* __restrict__ pairs,
    const int* __restrict__ gscan, int* __restrict__ rowptr,
    int* __restrict__ csr_src, int E, int NBL) {
  __shared__ int hist[512];
  __shared__ int ws8[8];
  int b = blockIdx.x, t = threadIdx.x;
  int base = gscan[b * NBL];
  int end = (b == NBKT - 1) ? E : gscan[(b + 1) * NBL];
  hist[t] = 0;
  __syncthreads();
  for (int i = base + t; i < end; i += 512) {
    unsigned d = (unsigned)(pairs[i] >> 32);
    atomicAdd(&hist[d & 511], 1);
  }
  __syncthreads();
  int v = hist[t];
  int lane = t & 63, wid = t >> 6;
  int s = v;
#pragma unroll
  for (int off = 1; off < 64; off <<= 1) {
    int u = __shfl_up(s, off);
    if (lane >= off) s += u;
  }
  if (lane == 63) ws8[wid] = s;
  __syncthreads();
  int add = 0;
  for (int w = 0; w < wid; w++) add += ws8[w];
  int excl = s + add - v;
  int node = (b << 9) + t;
  if (node < NUM_NODES) rowptr[node] = base + excl;
  if (b == NBKT - 1 && t == 0) rowptr[NUM_NODES] = E;
  __syncthreads();
  hist[t] = base + excl;
  __syncthreads();
  for (int i = base + t; i < end; i += 512) {
    unsigned long long p = pairs[i];
    unsigned d = (unsigned)(p >> 32);
    int pos = atomicAdd(&hist[d & 511], 1);
    csr_src[pos] = (int)(unsigned)p;
  }
}

__global__ __launch_bounds__(256) void calc_dinv2(const int* __restrict__ rowptr,
                                                  float* __restrict__ dinv,
                                                  int n) {
  int i = blockIdx.x * 256 + threadIdx.x;
  if (i < n) {
    int d = rowptr[i + 1] - rowptr[i];
    dinv[i] = d > 0 ? rsqrtf((float)d) : 0.f;
  }
}

// ---------------- chunked SpMM, XCD-pinned -----------------------------------
// chunk = blockIdx % 8 (round-robin block->XCD keeps one 2.25MB chunk per L2).
// Wave = 8 row-slots x 8 lanes; lane owns one uint (2 bf16 feats).
// y[row] = dinv[row] * sum dinv[s]*x[s]; out[row] += alpha*y[row].
__global__ __launch_bounds__(256) void spmm_chunk(
    const int* __restrict__ rowptr, const int* __restrict__ csr_src,
    const float* __restrict__ dinv, const unsigned int* __restrict__ xc,
    unsigned int* __restrict__ yc, float* __restrict__ out, int write_y) {
  int chunk = blockIdx.x & 7;
  int rowblk = blockIdx.x >> 3;
  int tid = threadIdx.x;
  int wave = tid >> 6, lane = tid & 63;
  int slot = lane >> 3, fl = lane & 7;
  int row = rowblk * 32 + wave * 8 + slot;
  bool act = row < NUM_NODES;
  int rr = act ? row : NUM_NODES - 1;
  int beg = rowptr[rr], end = rowptr[rr + 1];
  float wd = dinv[rr];
  const unsigned int* xq = xc + (size_t)chunk * NUM_NODES * 8 + fl;
  float a0 = 0.f, a1 = 0.f;
  int p = beg;
  for (; p + 4 <= end; p += 4) {
    int s0 = csr_src[p], s1 = csr_src[p + 1];
    int s2 = csr_src[p + 2], s3 = csr_src[p + 3];
    float c0 = dinv[s0], c1 = dinv[s1], c2 = dinv[s2], c3 = dinv[s3];
    unsigned v0 = xq[(size_t)s0 * 8];
    unsigned v1 = xq[(size_t)s1 * 8];
    unsigned v2 = xq[(size_t)s2 * 8];
    unsigned v3 = xq[(size_t)s3 * 8];
    a0 += c0 * bflo(v0) + c1 * bflo(v1) + c2 * bflo(v2) + c3 * bflo(v3);
    a1 += c0 * bfhi(v0) + c1 * bfhi(v1) + c2 * bfhi(v2) + c3 * bfhi(v3);
  }
  for (; p < end; p++) {
    int s0 = csr_src[p];
    float c0 = dinv[s0];
    unsigned v0 = xq[(size_t)s0 * 8];
    a0 += c0 * bflo(v0);
    a1 += c0 * bfhi(v0);
  }
  a0 *= wd;
  a1 *= wd;
  if (act) {
    if (write_y) {
      unsigned pk = (unsigned)f2bf(a0) | ((unsigned)f2bf(a1) << 16);
      yc[((size_t)chunk * NUM_NODES + row) * 8 + fl] = pk;
    }
    float2* op = (float2*)&out[(size_t)row * HID + chunk * 16 + fl * 2];
    float2 po = *op;
    po.x += ALPHA * a0;
    po.y += ALPHA * a1;
    *op = po;
  }
}

// ---------------- launcher ---------------------------------------------------
extern "C" void kernel_launch(void* const* d_in, const int* in_sizes, int n_in,
                              void* d_out, int out_size, void* d_ws,
                              size_t ws_size, hipStream_t stream) {
  const int* edge = (const int*)d_in[0];
  const float* item_feat = (const float*)d_in[1];
  const float* emb = (const float*)d_in[2];
  const float* W1 = (const float*)d_in[3];
  const float* b1 = (const float*)d_in[4];
  const float* g1 = (const float*)d_in[5];
  const float* be1 = (const float*)d_in[6];
  const float* W2 = (const float*)d_in[7];
  const float* b2 = (const float*)d_in[8];
  const float* g2 = (const float*)d_in[9];
  const float* be2 = (const float*)d_in[10];
  const float* W3 = (const float*)d_in[11];
  const float* b3 = (const float*)d_in[12];
  const float* mw = (const float*)d_in[13];
  float* out = (float*)d_out;

  const int E = in_sizes[0] / 2;
  const int* src = edge;
  const int* dst = edge + E;
  const int NBL = (E + 8191) / 8192;        // 245 P1 blocks
  const int nScan = NBKT * NBL;             // 33565
  const int NBs = (nScan + 255) / 256;      // 132

  // workspace layout (lifetimes disjoint on the single stream):
  //  [0, 40.96M)        h1 fp32 (meta aliases start); after build_e0:
  //                       pairs@0 (16M), rowptr@16M, dinv@16.5M, ghist@16.8M,
  //                       gscan@17M, bsum@17.2M, csr_src@17.5M (8M)
  //  [40.96M, 51.2M)    h2 fp32
  //  [51.2M, 71.68M)    h1b bf16; then xA_cm bf16 chunk-major (17.92M)
  //  [87.04M, 117.76M)  Af bf16; then xB_cm (17.92M)
  //  [104.96M, 122.88M) xC_cm (17.92M, overlaps tail of Af -- Af dead)
  //  [122.88M, ...)     W1t, W2t bf16
  char* ws = (char*)d_ws;
  float* h1 = (float*)(ws + 0);
  float* h2 = (float*)(ws + 40960000);
  unsigned short* h1b = (unsigned short*)(ws + 51200000);
  unsigned int* xA = (unsigned int*)(ws + 51200000);
  unsigned short* Af = (unsigned short*)(ws + 87040000);
  unsigned int* xB = (unsigned int*)(ws + 87040000);
  unsigned int* xC = (unsigned int*)(ws + 104960000);
  unsigned short* W1t = (unsigned short*)(ws + 122880000);
  unsigned short* W2t = (unsigned short*)(ws + 123666432);
  float* meta = h1;

  unsigned long long* pairs = (unsigned long long*)(ws + 0);
  int* rowptr = (int*)(ws + 16000000);
  float* dinv = (float*)(ws + 16500000);
  int* ghist = (int*)(ws + 16800000);
  int* gscan = (int*)(ws + 17000000);
  int* bsum = (int*)(ws + 17200000);
  int* csr_src = (int*)(ws + 17500000);

  // ---- casts ----
  cast_bf16<<<(NUM_ITEMS * FEAT_DIM / 8) / 256, 256, 0, stream>>>(item_feat, Af);
  transpose_cast<<<dim3(H1DIM / 32, FEAT_DIM / 32), dim3(32, 8), 0, stream>>>(
      W1, W1t, FEAT_DIM, H1DIM);
  transpose_cast<<<dim3(HID / 32, H1DIM / 32), dim3(32, 8), 0, stream>>>(
      W2, W2t, H1DIM, HID);

  // ---- item metadata MLP (bf16 MFMA GEMMs) ----
  gemm_mfma_bias<<<dim3(H1DIM / 128, (NUM_ITEMS + 127) / 128), 256, 0, stream>>>(
      Af, W1t, b1, h1, NUM_ITEMS, H1DIM, FEAT_DIM);
  ln_relu_w512_bf16<<<NUM_ITEMS, 256, 0, stream>>>(h1, g1, be1, h1b);
  gemm_mfma_bias<<<dim3(HID / 128, (NUM_ITEMS + 127) / 128), 256, 0, stream>>>(
      h1b, W2t, b2, h2, NUM_ITEMS, HID, H1DIM);
  ln_relu_w128<<<(NUM_ITEMS * 64) / 256, 256, 0, stream>>>(h2, g2, be2,
                                                           NUM_ITEMS);
  gemm3_norm4<<<NUM_ITEMS / 4, 128, 0, stream>>>(h2, W3, b3, meta);

  // ---- e0 -> out (fp32) + x0 chunk-major bf16 ----
  build_e0_cm<<<(NUM_NODES * 64) / 256, 256, 0, stream>>>(emb, meta, mw, xA,
                                                          out);

  // ---- atomic-free CSR build ----
  p1_hist<<<NBL, 256, 0, stream>>>(dst, ghist, E, NBL);
  scan_a<<<NBs, 256, 0, stream>>>(ghist, gscan, bsum, nScan);
  scan_b<<<1, 512, 0, stream>>>(bsum, NBs);
  scan_c<<<NBs, 256, 0, stream>>>(gscan, bsum, nScan);
  p1_scatter<<<NBL, 256, 0, stream>>>(src, dst, gscan, pairs, E, NBL);
  p2_build<<<NBKT, 512, 0, stream>>>(pairs, gscan, rowptr, csr_src, E, NBL);
  calc_dinv2<<<(NUM_NODES + 255) / 256, 256, 0, stream>>>(rowptr, dinv,
                                                          NUM_NODES);

  // ---- 3 propagation layers (chunked, XCD-pinned) ----
  const int RG = ((NUM_NODES + 31) / 32) * 8;  // 2188*8 = 17504 blocks
  spmm_chunk<<<RG, 256, 0, stream>>>(rowptr, csr_src, dinv, xA, xB, out, 1);
  spmm_chunk<<<RG, 256, 0, stream>>>(rowptr, csr_src, dinv, xB, xC, out, 1);
  spmm_chunk<<<RG, 256, 0, stream>>>(rowptr, csr_src, dinv, xC, nullptr, out, 0);
}

// Round 8
// 617.875 us; speedup vs baseline: 1.3110x; 1.3110x over previous
//
#include <hip/hip_runtime.h>
#include <hip/hip_bf16.h>

// ---------------- constants ----------------
#define NUM_USERS 50000
#define NUM_ITEMS 20000
#define NUM_NODES (NUM_USERS + NUM_ITEMS)
#define FEAT_DIM 768
#define HID 128
#define H1DIM 512
#define LN_EPS 1e-5f
#define ALPHA 0.25f
#define NBKT 137  // ceil(70000/512) coarse buckets

typedef __attribute__((ext_vector_type(8))) short short8;
typedef __attribute__((ext_vector_type(4))) float floatx4;

// bf16 round-to-nearest-even
static __device__ inline unsigned short f2bf(float f) {
  unsigned int u = __float_as_uint(f);
  u += 0x7fffu + ((u >> 16) & 1u);
  return (unsigned short)(u >> 16);
}
static __device__ inline float bflo(unsigned int u) {
  return __uint_as_float(u << 16);
}
static __device__ inline float bfhi(unsigned int u) {
  return __uint_as_float(u & 0xffff0000u);
}

// -------- cast fp32 -> bf16, 8 elements/thread, exact grid -------------------
__global__ __launch_bounds__(256) void cast_bf16(
    const float* __restrict__ in, unsigned short* __restrict__ out) {
  size_t i = (size_t)blockIdx.x * 256 + threadIdx.x;
  float4 u = ((const float4*)in)[i * 2];
  float4 v = ((const float4*)in)[i * 2 + 1];
  union { unsigned short s[8]; uint4 q; } p;
  p.s[0] = f2bf(u.x); p.s[1] = f2bf(u.y); p.s[2] = f2bf(u.z); p.s[3] = f2bf(u.w);
  p.s[4] = f2bf(v.x); p.s[5] = f2bf(v.y); p.s[6] = f2bf(v.z); p.s[7] = f2bf(v.w);
  ((uint4*)out)[i] = p.q;
}

// -------- transpose+cast: W[K x N] fp32 -> Wt[N x K] bf16 --------------------
__global__ __launch_bounds__(256) void transpose_cast(
    const float* __restrict__ W, unsigned short* __restrict__ Wt,
    int K, int N) {
  __shared__ float tile[32][33];
  int tx = threadIdx.x, ty = threadIdx.y;
  int bx = blockIdx.x, by = blockIdx.y;
#pragma unroll
  for (int kk = 0; kk < 4; kk++)
    tile[ty + kk * 8][tx] = W[(size_t)(by * 32 + ty + kk * 8) * N + bx * 32 + tx];
  __syncthreads();
#pragma unroll
  for (int kk = 0; kk < 4; kk++)
    Wt[(size_t)(bx * 32 + ty + kk * 8) * K + by * 32 + tx] =
        f2bf(tile[tx][ty + kk * 8]);
}

// -------- bf16 MFMA GEMM: C(MxN) fp32 = A(MxK) . Bt(NxK)^T + bias ------------
__global__ __launch_bounds__(256) void gemm_mfma_bias(
    const unsigned short* __restrict__ A, const unsigned short* __restrict__ Bt,
    const float* __restrict__ bias, float* __restrict__ C,
    int M, int N, int K) {
  __shared__ __align__(16) unsigned short As[128 * 32];
  __shared__ __align__(16) unsigned short Bs[128 * 32];
  const int tid = threadIdx.x;
  const int wave = tid >> 6, lane = tid & 63;
  const int quad = lane >> 4, l16 = lane & 15;
  const int wm = wave >> 1, wn = wave & 1;
  const int bm = blockIdx.y * 128, bn = blockIdx.x * 128;

  floatx4 acc[4][4];
#pragma unroll
  for (int i = 0; i < 4; i++)
#pragma unroll
    for (int j = 0; j < 4; j++) acc[i][j] = (floatx4){0.f, 0.f, 0.f, 0.f};

  const int srow = lane >> 2;
  const int scol = (lane & 3) * 8;

  for (int k0 = 0; k0 < K; k0 += 32) {
#pragma unroll
    for (int i = 0; i < 2; i++) {
      int c = wave * 2 + i;
      int arow = bm + c * 16 + srow;
      if (arow >= M) arow = M - 1;
      const unsigned short* ga = A + (size_t)arow * K + k0 + scol;
      __builtin_amdgcn_global_load_lds(
          (const __attribute__((address_space(1))) unsigned int*)(uintptr_t)ga,
          (__attribute__((address_space(3))) unsigned int*)(uintptr_t)(As + c * 512),
          16, 0, 0);
      int brow = bn + c * 16 + srow;
      const unsigned short* gb = Bt + (size_t)brow * K + k0 + scol;
      __builtin_amdgcn_global_load_lds(
          (const __attribute__((address_space(1))) unsigned int*)(uintptr_t)gb,
          (__attribute__((address_space(3))) unsigned int*)(uintptr_t)(Bs + c * 512),
          16, 0, 0);
    }
    __syncthreads();

    short8 af[4], bf[4];
#pragma unroll
    for (int i = 0; i < 4; i++) {
      af[i] = *(const short8*)&As[(wm * 64 + i * 16 + l16) * 32 + quad * 8];
      bf[i] = *(const short8*)&Bs[(wn * 64 + i * 16 + l16) * 32 + quad * 8];
    }
#pragma unroll
    for (int i = 0; i < 4; i++)
#pragma unroll
      for (int j = 0; j < 4; j++)
        acc[i][j] = __builtin_amdgcn_mfma_f32_16x16x32_bf16(af[i], bf[j],
                                                            acc[i][j], 0, 0, 0);
    __syncthreads();
  }

#pragma unroll
  for (int i = 0; i < 4; i++) {
    int row0 = bm + wm * 64 + i * 16 + quad * 4;
#pragma unroll
    for (int j = 0; j < 4; j++) {
      int col = bn + wn * 64 + j * 16 + l16;
      float bv = bias[col];
#pragma unroll
      for (int r = 0; r < 4; r++) {
        int row = row0 + r;
        if (row < M) C[(size_t)row * N + col] = acc[i][j][r] + bv;
      }
    }
  }
}

// ---- LayerNorm+ReLU width 512, fp32 in -> bf16 out --------------------------
__global__ __launch_bounds__(256) void ln_relu_w512_bf16(
    const float* __restrict__ X, const float* __restrict__ g,
    const float* __restrict__ be, unsigned short* __restrict__ O) {
  int row = blockIdx.x, t = threadIdx.x;
  const float* x = X + (size_t)row * H1DIM;
  float v0 = x[t], v1 = x[t + 256];
  float s = v0 + v1, q = v0 * v0 + v1 * v1;
#pragma unroll
  for (int off = 32; off > 0; off >>= 1) {
    s += __shfl_down(s, off);
    q += __shfl_down(q, off);
  }
  __shared__ float ss[4], qq[4];
  int lane = t & 63, wid = t >> 6;
  if (lane == 0) { ss[wid] = s; qq[wid] = q; }
  __syncthreads();
  float S = ss[0] + ss[1] + ss[2] + ss[3];
  float Q = qq[0] + qq[1] + qq[2] + qq[3];
  float mu = S * (1.f / 512.f);
  float var = Q * (1.f / 512.f) - mu * mu;
  float rs = rsqrtf(var + LN_EPS);
  float y0 = (v0 - mu) * rs * g[t] + be[t];
  float y1 = (v1 - mu) * rs * g[t + 256] + be[t + 256];
  unsigned short* o = O + (size_t)row * H1DIM;
  o[t] = f2bf(fmaxf(y0, 0.f));
  o[t + 256] = f2bf(fmaxf(y1, 0.f));
}

// ---------------- LayerNorm+ReLU, width 128, one wave per row ----------------
__global__ __launch_bounds__(256) void ln_relu_w128(
    float* __restrict__ X, const float* __restrict__ g,
    const float* __restrict__ be, int rows) {
  int gwid = (blockIdx.x * blockDim.x + threadIdx.x) >> 6;
  if (gwid >= rows) return;
  int lane = threadIdx.x & 63;
  float* x = X + (size_t)gwid * HID;
  float v0 = x[lane], v1 = x[lane + 64];
  float s = v0 + v1, q = v0 * v0 + v1 * v1;
#pragma unroll
  for (int off = 32; off > 0; off >>= 1) {
    s += __shfl_down(s, off);
    q += __shfl_down(q, off);
  }
  s = __shfl(s, 0);
  q = __shfl(q, 0);
  float mu = s * (1.f / 128.f);
  float var = q * (1.f / 128.f) - mu * mu;
  float rs = rsqrtf(var + LN_EPS);
  float y0 = (v0 - mu) * rs * g[lane] + be[lane];
  float y1 = (v1 - mu) * rs * g[lane + 64] + be[lane + 64];
  x[lane] = fmaxf(y0, 0.f);
  x[lane + 64] = fmaxf(y1, 0.f);
}

// ---- GEMM3 (128x128) + L2-normalize, 4 rows/block ---------------------------
__global__ __launch_bounds__(128) void gemm3_norm4(
    const float* __restrict__ H, const float* __restrict__ W3,
    const float* __restrict__ b3, float* __restrict__ meta) {
  int r0 = blockIdx.x * 4, t = threadIdx.x;
  __shared__ float hrow[4][HID];
#pragma unroll
  for (int r = 0; r < 4; r++) hrow[r][t] = H[(size_t)(r0 + r) * HID + t];
  __syncthreads();
  float s0 = 0.f, s1 = 0.f, s2 = 0.f, s3 = 0.f;
#pragma unroll 4
  for (int k = 0; k < HID; k++) {
    float w = W3[k * HID + t];
    s0 = fmaf(hrow[0][k], w, s0);
    s1 = fmaf(hrow[1][k], w, s1);
    s2 = fmaf(hrow[2][k], w, s2);
    s3 = fmaf(hrow[3][k], w, s3);
  }
  float b = b3[t];
  s0 += b; s1 += b; s2 += b; s3 += b;
  float q0 = s0 * s0, q1 = s1 * s1, q2 = s2 * s2, q3 = s3 * s3;
#pragma unroll
  for (int off = 32; off > 0; off >>= 1) {
    q0 += __shfl_down(q0, off);
    q1 += __shfl_down(q1, off);
    q2 += __shfl_down(q2, off);
    q3 += __shfl_down(q3, off);
  }
  __shared__ float qs[4][2];
  if ((t & 63) == 0) {
    int w = t >> 6;
    qs[0][w] = q0; qs[1][w] = q1; qs[2][w] = q2; qs[3][w] = q3;
  }
  __syncthreads();
  float n0 = fmaxf(sqrtf(qs[0][0] + qs[0][1]), 1e-12f);
  float n1 = fmaxf(sqrtf(qs[1][0] + qs[1][1]), 1e-12f);
  float n2 = fmaxf(sqrtf(qs[2][0] + qs[2][1]), 1e-12f);
  float n3 = fmaxf(sqrtf(qs[3][0] + qs[3][1]), 1e-12f);
  meta[(size_t)(r0 + 0) * HID + t] = s0 / n0;
  meta[(size_t)(r0 + 1) * HID + t] = s1 / n1;
  meta[(size_t)(r0 + 2) * HID + t] = s2 / n2;
  meta[(size_t)(r0 + 3) * HID + t] = s3 / n3;
}

// --------- build e0: out = alpha*e0 (fp32), x0 chunk-major bf16 (4x32) -------
// x0_cm[chunk][node][32 feats] = 16 uints per (chunk,node). Thread = one uint.
__global__ __launch_bounds__(256) void build_e0_cm4(
    const float* __restrict__ emb, const float* __restrict__ meta,
    const float* __restrict__ mw_p, unsigned int* __restrict__ x0c,
    float* __restrict__ out) {
  size_t i = (size_t)blockIdx.x * 256 + threadIdx.x;  // 70000*64 uints, exact
  int node = (int)(i >> 6);
  int u6 = (int)(i & 63);
  int chunk = u6 >> 4, fl = u6 & 15;
  int f0 = chunk * 32 + fl * 2;
  float2 e = *(const float2*)&emb[(size_t)node * HID + f0];
  if (node >= NUM_USERS) {
    float2 m = *(const float2*)&meta[(size_t)(node - NUM_USERS) * HID + f0];
    float w = mw_p[0];
    e.x += w * m.x;
    e.y += w * m.y;
  }
  *(float2*)&out[(size_t)node * HID + f0] = make_float2(ALPHA * e.x, ALPHA * e.y);
  unsigned pk = (unsigned)f2bf(e.x) | ((unsigned)f2bf(e.y) << 16);
  x0c[((size_t)chunk * NUM_NODES + node) * 16 + fl] = pk;
}

// ======== atomic-free CSR build: two-level bucket sort =======================
__global__ __launch_bounds__(256) void p1_hist(const int* __restrict__ dst,
                                               int* __restrict__ ghist,
                                               int E, int NBL) {
  __shared__ int h[NBKT];
  int t = threadIdx.x;
  if (t < NBKT) h[t] = 0;
  __syncthreads();
  int base = blockIdx.x * 8192;
  for (int i = t; i < 8192; i += 256) {
    int e = base + i;
    if (e < E) atomicAdd(&h[dst[e] >> 9], 1);
  }
  __syncthreads();
  if (t < NBKT) ghist[t * NBL + blockIdx.x] = h[t];
}

__global__ __launch_bounds__(256) void scan_a(const int* __restrict__ in,
                                              int* __restrict__ outp,
                                              int* __restrict__ bsum, int n) {
  int i = blockIdx.x * 256 + threadIdx.x;
  int v = (i < n) ? in[i] : 0;
  int lane = threadIdx.x & 63, wid = threadIdx.x >> 6;
  int s = v;
#pragma unroll
  for (int off = 1; off < 64; off <<= 1) {
    int u = __shfl_up(s, off);
    if (lane >= off) s += u;
  }
  __shared__ int wsum[4];
  if (lane == 63) wsum[wid] = s;
  __syncthreads();
  int add = 0;
  for (int w = 0; w < wid; w++) add += wsum[w];
  int incl = s + add;
  if (i < n) outp[i] = incl - v;
  if (threadIdx.x == 255) bsum[blockIdx.x] = incl;
}

__global__ __launch_bounds__(512) void scan_b(int* __restrict__ bsum, int nb) {
  int t = threadIdx.x;
  int v = (t < nb) ? bsum[t] : 0;
  int lane = t & 63, wid = t >> 6;
  int s = v;
#pragma unroll
  for (int off = 1; off < 64; off <<= 1) {
    int u = __shfl_up(s, off);
    if (lane >= off) s += u;
  }
  __shared__ int ws[8];
  if (lane == 63) ws[wid] = s;
  __syncthreads();
  int add = 0;
  for (int w = 0; w < wid; w++) add += ws[w];
  if (t < nb) bsum[t] = s + add - v;
}

__global__ __launch_bounds__(256) void scan_c(int* __restrict__ outp,
                                              const int* __restrict__ bsum,
                                              int n) {
  int i = blockIdx.x * 256 + threadIdx.x;
  if (i < n) outp[i] += bsum[blockIdx.x];
}

__global__ __launch_bounds__(256) void p1_scatter(
    const int* __restrict__ src, const int* __restrict__ dst,
    const int* __restrict__ gscan, unsigned long long* __restrict__ pairs,
    int E, int NBL) {
  __shared__ int cur[NBKT];
  int t = threadIdx.x;
  if (t < NBKT) cur[t] = gscan[t * NBL + blockIdx.x];
  __syncthreads();
  int base = blockIdx.x * 8192;
  for (int i = t; i < 8192; i += 256) {
    int e = base + i;
    if (e < E) {
      int d = dst[e];
      int pos = atomicAdd(&cur[d >> 9], 1);
      pairs[pos] = ((unsigned long long)(unsigned)d << 32) | (unsigned)src[e];
    }
  }
}

__global__ __launch_bounds__(512) void p2_build(
    const unsigned long long* __restrict__ pairs,
    const int* __restrict__ gscan, int* __restrict__ rowptr,
    int* __restrict__ csr_src, int E, int NBL) {
  __shared__ int hist[512];
  __shared__ int ws8[8];
  int b = blockIdx.x, t = threadIdx.x;
  int base = gscan[b * NBL];
  int end = (b == NBKT - 1) ? E : gscan[(b + 1) * NBL];
  hist[t] = 0;
  __syncthreads();
  for (int i = base + t; i < end; i += 512) {
    unsigned d = (unsigned)(pairs[i] >> 32);
    atomicAdd(&hist[d & 511], 1);
  }
  __syncthreads();
  int v = hist[t];
  int lane = t & 63, wid = t >> 6;
  int s = v;
#pragma unroll
  for (int off = 1; off < 64; off <<= 1) {
    int u = __shfl_up(s, off);
    if (lane >= off) s += u;
  }
  if (lane == 63) ws8[wid] = s;
  __syncthreads();
  int add = 0;
  for (int w = 0; w < wid; w++) add += ws8[w];
  int excl = s + add - v;
  int node = (b << 9) + t;
  if (node < NUM_NODES) rowptr[node] = base + excl;
  if (b == NBKT - 1 && t == 0) rowptr[NUM_NODES] = E;
  __syncthreads();
  hist[t] = base + excl;
  __syncthreads();
  for (int i = base + t; i < end; i += 512) {
    unsigned long long p = pairs[i];
    unsigned d = (unsigned)(p >> 32);
    int pos = atomicAdd(&hist[d & 511], 1);
    csr_src[pos] = (int)(unsigned)p;
  }
}

__global__ __launch_bounds__(256) void calc_dinv2(const int* __restrict__ rowptr,
                                                  float* __restrict__ dinv,
                                                  int n) {
  int i = blockIdx.x * 256 + threadIdx.x;
  if (i < n) {
    int d = rowptr[i + 1] - rowptr[i];
    dinv[i] = d > 0 ? rsqrtf((float)d) : 0.f;
  }
}

// ---- pack (src, dinv[src]) per edge: removes the random dinv gather from spmm
__global__ __launch_bounds__(256) void pack_edges(
    const int* __restrict__ csr_src, const float* __restrict__ dinv,
    uint2* __restrict__ epack, int E) {
  int i = blockIdx.x * 256 + threadIdx.x;
  if (i < E) {
    int s = csr_src[i];
    epack[i] = make_uint2((unsigned)s, __float_as_uint(dinv[s]));
  }
}

// ---------------- chunked SpMM v2: 4 chunks x 32 feats, XCD-pinned -----------
// chunk = blockIdx & 3 (with blk->XCD = blk%8, each XCD sees one chunk).
// Wave = 8 row-slots x 8 lanes; lane owns one uint2 (4 bf16 feats).
// y[row] = dinv[row] * sum coeff_e * x[src_e]; out[row] += alpha*y[row].
__global__ __launch_bounds__(256) void spmm_chunk4(
    const int* __restrict__ rowptr, const uint2* __restrict__ epack,
    const float* __restrict__ dinv, const uint2* __restrict__ xc,
    uint2* __restrict__ yc, float* __restrict__ out, int write_y) {
  int chunk = blockIdx.x & 3;
  int rowblk = blockIdx.x >> 2;
  int tid = threadIdx.x;
  int wave = tid >> 6, lane = tid & 63;
  int slot = lane >> 3, fl = lane & 7;
  int row = rowblk * 32 + wave * 8 + slot;
  bool act = row < NUM_NODES;
  int rr = act ? row : NUM_NODES - 1;
  int beg = rowptr[rr], end = rowptr[rr + 1];
  float wd = dinv[rr];
  const uint2* xq = xc + (size_t)chunk * NUM_NODES * 8 + fl;  // 8 uint2/node
  float a0 = 0.f, a1 = 0.f, a2 = 0.f, a3 = 0.f;
  int p = beg;
  for (; p + 4 <= end; p += 4) {
    uint2 e0 = epack[p], e1 = epack[p + 1];
    uint2 e2 = epack[p + 2], e3 = epack[p + 3];
    float c0 = __uint_as_float(e0.y), c1 = __uint_as_float(e1.y);
    float c2 = __uint_as_float(e2.y), c3 = __uint_as_float(e3.y);
    uint2 v0 = xq[(size_t)e0.x * 8];
    uint2 v1 = xq[(size_t)e1.x * 8];
    uint2 v2 = xq[(size_t)e2.x * 8];
    uint2 v3 = xq[(size_t)e3.x * 8];
    a0 += c0 * bflo(v0.x) + c1 * bflo(v1.x) + c2 * bflo(v2.x) + c3 * bflo(v3.x);
    a1 += c0 * bfhi(v0.x) + c1 * bfhi(v1.x) + c2 * bfhi(v2.x) + c3 * bfhi(v3.x);
    a2 += c0 * bflo(v0.y) + c1 * bflo(v1.y) + c2 * bflo(v2.y) + c3 * bflo(v3.y);
    a3 += c0 * bfhi(v0.y) + c1 * bfhi(v1.y) + c2 * bfhi(v2.y) + c3 * bfhi(v3.y);
  }
  for (; p < end; p++) {
    uint2 e0 = epack[p];
    float c0 = __uint_as_float(e0.y);
    uint2 v0 = xq[(size_t)e0.x * 8];
    a0 += c0 * bflo(v0.x);
    a1 += c0 * bfhi(v0.x);
    a2 += c0 * bflo(v0.y);
    a3 += c0 * bfhi(v0.y);
  }
  a0 *= wd; a1 *= wd; a2 *= wd; a3 *= wd;
  if (act) {
    if (write_y) {
      unsigned p0 = (unsigned)f2bf(a0) | ((unsigned)f2bf(a1) << 16);
      unsigned p1 = (unsigned)f2bf(a2) | ((unsigned)f2bf(a3) << 16);
      yc[((size_t)chunk * NUM_NODES + row) * 8 + fl] = make_uint2(p0, p1);
    }
    float4* op = (float4*)&out[(size_t)row * HID + chunk * 32 + fl * 4];
    float4 po = *op;
    po.x += ALPHA * a0;
    po.y += ALPHA * a1;
    po.z += ALPHA * a2;
    po.w += ALPHA * a3;
    *op = po;
  }
}

// ---------------- launcher ---------------------------------------------------
extern "C" void kernel_launch(void* const* d_in, const int* in_sizes, int n_in,
                              void* d_out, int out_size, void* d_ws,
                              size_t ws_size, hipStream_t stream) {
  const int* edge = (const int*)d_in[0];
  const float* item_feat = (const float*)d_in[1];
  const float* emb = (const float*)d_in[2];
  const float* W1 = (const float*)d_in[3];
  const float* b1 = (const float*)d_in[4];
  const float* g1 = (const float*)d_in[5];
  const float* be1 = (const float*)d_in[6];
  const float* W2 = (const float*)d_in[7];
  const float* b2 = (const float*)d_in[8];
  const float* g2 = (const float*)d_in[9];
  const float* be2 = (const float*)d_in[10];
  const float* W3 = (const float*)d_in[11];
  const float* b3 = (const float*)d_in[12];
  const float* mw = (const float*)d_in[13];
  float* out = (float*)d_out;

  const int E = in_sizes[0] / 2;
  const int* src = edge;
  const int* dst = edge + E;
  const int NBL = (E + 8191) / 8192;        // 245 P1 blocks
  const int nScan = NBKT * NBL;             // 33565
  const int NBs = (nScan + 255) / 256;      // 132

  // workspace layout (lifetimes disjoint on the single stream):
  //  [0, 40.96M)        h1 fp32 (meta aliases start); after build_e0:
  //                       pairs@0 (16M) -> epack@0 (16M, pairs dead),
  //                       rowptr@16M, dinv@16.5M, ghist@16.8M,
  //                       gscan@17M, bsum@17.2M, csr_src@17.5M (8M)
  //  [40.96M, 51.2M)    h2 fp32
  //  [51.2M, 71.68M)    h1b bf16; then xA_cm bf16 chunk-major (17.92M)
  //  [87.04M, 117.76M)  Af bf16; then xB_cm (17.92M)
  //  [104.96M, 122.88M) xC_cm (17.92M, Af dead by then)
  //  [122.88M, ...)     W1t, W2t bf16
  char* ws = (char*)d_ws;
  float* h1 = (float*)(ws + 0);
  float* h2 = (float*)(ws + 40960000);
  unsigned short* h1b = (unsigned short*)(ws + 51200000);
  uint2* xA = (uint2*)(ws + 51200000);
  unsigned short* Af = (unsigned short*)(ws + 87040000);
  uint2* xB = (uint2*)(ws + 87040000);
  uint2* xC = (uint2*)(ws + 104960000);
  unsigned short* W1t = (unsigned short*)(ws + 122880000);
  unsigned short* W2t = (unsigned short*)(ws + 123666432);
  float* meta = h1;

  unsigned long long* pairs = (unsigned long long*)(ws + 0);
  uint2* epack = (uint2*)(ws + 0);  // aliases pairs; pairs dead after p2_build
  int* rowptr = (int*)(ws + 16000000);
  float* dinv = (float*)(ws + 16500000);
  int* ghist = (int*)(ws + 16800000);
  int* gscan = (int*)(ws + 17000000);
  int* bsum = (int*)(ws + 17200000);
  int* csr_src = (int*)(ws + 17500000);

  // ---- casts ----
  cast_bf16<<<(NUM_ITEMS * FEAT_DIM / 8) / 256, 256, 0, stream>>>(item_feat, Af);
  transpose_cast<<<dim3(H1DIM / 32, FEAT_DIM / 32), dim3(32, 8), 0, stream>>>(
      W1, W1t, FEAT_DIM, H1DIM);
  transpose_cast<<<dim3(HID / 32, H1DIM / 32), dim3(32, 8), 0, stream>>>(
      W2, W2t, H1DIM, HID);

  // ---- item metadata MLP (bf16 MFMA GEMMs) ----
  gemm_mfma_bias<<<dim3(H1DIM / 128, (NUM_ITEMS + 127) / 128), 256, 0, stream>>>(
      Af, W1t, b1, h1, NUM_ITEMS, H1DIM, FEAT_DIM);
  ln_relu_w512_bf16<<<NUM_ITEMS, 256, 0, stream>>>(h1, g1, be1, h1b);
  gemm_mfma_bias<<<dim3(HID / 128, (NUM_ITEMS + 127) / 128), 256, 0, stream>>>(
      h1b, W2t, b2, h2, NUM_ITEMS, HID, H1DIM);
  ln_relu_w128<<<(NUM_ITEMS * 64) / 256, 256, 0, stream>>>(h2, g2, be2,
                                                           NUM_ITEMS);
  gemm3_norm4<<<NUM_ITEMS / 4, 128, 0, stream>>>(h2, W3, b3, meta);

  // ---- e0 -> out (fp32) + x0 chunk-major bf16 (4 chunks x 32) ----
  build_e0_cm4<<<(NUM_NODES * 64) / 256, 256, 0, stream>>>(
      emb, meta, mw, (unsigned int*)xA, out);

  // ---- atomic-free CSR build ----
  p1_hist<<<NBL, 256, 0, stream>>>(dst, ghist, E, NBL);
  scan_a<<<NBs, 256, 0, stream>>>(ghist, gscan, bsum, nScan);
  scan_b<<<1, 512, 0, stream>>>(bsum, NBs);
  scan_c<<<NBs, 256, 0, stream>>>(gscan, bsum, nScan);
  p1_scatter<<<NBL, 256, 0, stream>>>(src, dst, gscan, pairs, E, NBL);
  p2_build<<<NBKT, 512, 0, stream>>>(pairs, gscan, rowptr, csr_src, E, NBL);
  calc_dinv2<<<(NUM_NODES + 255) / 256, 256, 0, stream>>>(rowptr, dinv,
                                                          NUM_NODES);
  pack_edges<<<(E + 255) / 256, 256, 0, stream>>>(csr_src, dinv, epack, E);

  // ---- 3 propagation layers (4-chunked, XCD-pinned, packed edges) ----
  const int RG = ((NUM_NODES + 31) / 32) * 4;  // 2188*4 = 8752 blocks
  spmm_chunk4<<<RG, 256, 0, stream>>>(rowptr, epack, dinv, xA, xB, out, 1);
  spmm_chunk4<<<RG, 256, 0, stream>>>(rowptr, epack, dinv, xB, xC, out, 1);
  spmm_chunk4<<<RG, 256, 0, stream>>>(rowptr, epack, dinv, xC, nullptr, out, 0);
}